// Round 5
// baseline (525.862 us; speedup 1.0000x reference)
//
#include <hip/hip_runtime.h>

typedef unsigned short u16;
typedef __attribute__((ext_vector_type(8))) short bf16x8;   // MFMA A/B frag
typedef __attribute__((ext_vector_type(4))) float f32x4;    // MFMA C/D frag
typedef __attribute__((ext_vector_type(4))) unsigned short us4;
typedef __attribute__((ext_vector_type(8))) unsigned short us8;

__device__ __forceinline__ u16 f2us(float f) {
  union { float f; unsigned u; } a; a.f = f;
  unsigned u = a.u;
  u += 0x7fffu + ((u >> 16) & 1u);   // RNE to bf16
  return (u16)(u >> 16);
}
__device__ __forceinline__ float us2f(u16 h) {
  union { unsigned u; float f; } a; a.u = ((unsigned)h) << 16;
  return a.f;
}

#define GLDS(g, l) __builtin_amdgcn_global_load_lds( \
    (const __attribute__((address_space(1))) void*)(g), \
    (__attribute__((address_space(3))) void*)(l), 16, 0, 0)

// ---------------------------------------------------------------------------
// merged fp32 -> bf16 conversion: x (16384 blocks) + 4 weights (1024 each)
// ---------------------------------------------------------------------------
__global__ __launch_bounds__(256) void convert_all(
    const float* __restrict__ x, const float* __restrict__ Wq,
    const float* __restrict__ Wk, const float* __restrict__ Wv,
    const float* __restrict__ Wp, u16* __restrict__ xb, u16* __restrict__ wb) {
  const int bid = blockIdx.x;
  const float* src;
  u16* dst;
  int off;
  if (bid < 16384) {
    src = x; dst = xb; off = bid * 256 + threadIdx.x;
  } else {
    const int w = (bid - 16384) >> 10;
    const int lb = (bid - 16384) & 1023;
    src = (w == 0) ? Wq : (w == 1) ? Wk : (w == 2) ? Wv : Wp;
    dst = wb + (size_t)w * 1048576;
    off = lb * 256 + threadIdx.x;
  }
  f32x4 v = ((const f32x4*)src)[off];
  us4 o;
  o.x = f2us(v.x); o.y = f2us(v.y); o.z = f2us(v.z); o.w = f2us(v.w);
  ((us4*)dst)[off] = o;
}

// ---------------------------------------------------------------------------
// 256x256 pipelined bf16 GEMM (C = scale * A · B^T). Quadrant order
// (0,0)->(0,1)->(1,1)->(1,0); every MFMA's operands were ds_read >=1 phase
// earlier. Stage schedule (deterministically race-free: a region is only
// DMA-overwritten after a barrier that follows the MFMA which lgkm-retired
// all reads of it):
//   p1: A(t+1)h1 + B(t+1)h0 ; read fb1 ; MFMA A0·B0
//   p2: B(t+1)h1            ; read fa1 ; MFMA A0·B1
//   p3: (pure MFMA, LDS catch-up)      ; MFMA A1·B1
//   p4: A(t+2)h0 ; vmcnt(2) ; MFMA A1·B0 ; THEN refill fa0/fb0 from nxt
// vmcnt ledger: 10 outstanding after p4's stage; vmcnt(2) drains all of
// A(t+1),B(t+1) before the next-tile pre-reads; leaves A(t+2)h0 in flight.
// EP: 0 = bf16 store; 2 = fp32 store; 3 = QKV mode (A fixed, B/C by z,
//     z==2 stores transposed into Vt[b][d][s], 4096-row batches).
// ---------------------------------------------------------------------------
#define MFMA_Q(FA, FB, QR, QC)                                                   \
  do {                                                                           \
    __builtin_amdgcn_s_setprio(1);                                               \
    _Pragma("unroll") for (int m = 0; m < 4; ++m)                                \
    _Pragma("unroll") for (int n = 0; n < 2; ++n)                                \
    _Pragma("unroll") for (int s = 0; s < 2; ++s)                                \
      acc[(QR)*4 + m][(QC)*2 + n] = __builtin_amdgcn_mfma_f32_16x16x32_bf16(     \
          FA[m][s], FB[n][s], acc[(QR)*4 + m][(QC)*2 + n], 0, 0, 0);             \
    __builtin_amdgcn_s_setprio(0);                                               \
  } while (0)

#define STAGE_A(buf, h, kb)                                                  \
  do {                                                                       \
    const int su_ = (h) * 128 * lda + (kb);                                  \
    GLDS(Ap + aoff0 + su_, As + (buf) * 16384 + (h) * 8192 + ldst0);         \
    GLDS(Ap + aoff1 + su_, As + (buf) * 16384 + (h) * 8192 + ldst1);         \
  } while (0)

#define STAGE_B(buf, h, kb)                                                  \
  do {                                                                       \
    const int su_ = (h) * 128 * ldb + (kb);                                  \
    GLDS(Bp + boff0 + su_, Bs + (buf) * 16384 + (h) * 8192 + ldst0);         \
    GLDS(Bp + boff1 + su_, Bs + (buf) * 16384 + (h) * 8192 + ldst1);         \
  } while (0)

template <int EP>
__global__ __launch_bounds__(512, 2) void gemm256(
    const u16* __restrict__ A0, const u16* __restrict__ A1,
    const u16* __restrict__ A2, const u16* __restrict__ A3,
    const u16* __restrict__ B0, const u16* __restrict__ B1,
    const u16* __restrict__ B2, const u16* __restrict__ B3,
    void* C0, void* C1, void* C2, void* C3,
    int K, int lda, int ldb, int ldc, float scale) {
  __shared__ u16 As[32768];   // 2 buf x 2 half x 128x64
  __shared__ u16 Bs[32768];
  const int tid = threadIdx.x;
  const int lane = tid & 63;
  const int wid = tid >> 6;
  const int wm = wid >> 2;    // 0..1 -> A half
  const int wn = wid & 3;     // 0..3 -> 64-col slice
  const int z = blockIdx.z;
  const u16* A = (z == 0) ? A0 : (z == 1) ? A1 : (z == 2) ? A2 : A3;
  const u16* B = (z == 0) ? B0 : (z == 1) ? B1 : (z == 2) ? B2 : B3;
  void* C = (z == 0) ? C0 : (z == 1) ? C1 : (z == 2) ? C2 : C3;

  // T1: bijective XCD swizzle (all grids have nwg % 8 == 0)
  const int gx = gridDim.x;
  const int nwg = gx * (int)gridDim.y;
  const int orig = (int)blockIdx.y * gx + (int)blockIdx.x;
  const int swz = (orig & 7) * (nwg >> 3) + (orig >> 3);
  const long trow = (long)(swz / gx) * 256;
  const long tcol = (long)(swz % gx) * 256;

  // hoisted per-thread staging offsets (u16 elements)
  const int srow = tid >> 3;                     // 0..63
  const int sgrp = (tid & 7) ^ (srow & 7);       // inverse T2 swizzle on source
  const int aoff0 = srow * lda + sgrp * 8;
  const int aoff1 = aoff0 + (lda << 6);
  const int boff0 = srow * ldb + sgrp * 8;
  const int boff1 = boff0 + (ldb << 6);
  const int ldst0 = (tid & ~63) * 8;             // wave-uniform LDS dest
  const int ldst1 = ldst0 + 4096;
  const u16* Ap = A + trow * lda;
  const u16* Bp = B + tcol * ldb;

  // hoisted per-lane LDS read offsets (u16 elements): row + swizzled col
  const int l15x64 = (lane & 15) * 64;
  const int cs0 = ((((lane >> 4) * 8)) ^ ((lane & 7) * 8)) + l15x64;
  const int cs1 = ((32 + ((lane >> 4) * 8)) ^ ((lane & 7) * 8)) + l15x64;

  f32x4 acc[8][4];
  f32x4 zero = {0.f, 0.f, 0.f, 0.f};
#pragma unroll
  for (int m = 0; m < 8; ++m)
#pragma unroll
    for (int n = 0; n < 4; ++n) acc[m][n] = zero;

  const int NT = K >> 6;
  const int kmask = K - 1;   // K is a power of two

  // fragment registers (static indexing only)
  bf16x8 fa0[4][2], fa1[4][2], fb0[2][2], fb1[2][2];

  // prologue: stage A(0) full, B(0) full, A(1)h0 (10 loads); drain all but
  // A(1)h0; publish; pre-read tile0's A0/B0 fragments.
  STAGE_A(0, 0, 0);
  STAGE_A(0, 1, 0);
  STAGE_B(0, 0, 0);
  STAGE_B(0, 1, 0);
  STAGE_A(1, 0, 64 & kmask);
  asm volatile("s_waitcnt vmcnt(2)" ::: "memory");
  __builtin_amdgcn_s_barrier();
  {
    const u16* Ac = As + wm * 8192;
    const u16* Bc = Bs + (wn >> 1) * 8192 + (wn & 1) * 4096;
#pragma unroll
    for (int m = 0; m < 4; ++m) {
      fa0[m][0] = *(const bf16x8*)(Ac + m * 1024 + cs0);
      fa0[m][1] = *(const bf16x8*)(Ac + m * 1024 + cs1);
    }
#pragma unroll
    for (int n = 0; n < 2; ++n) {
      fb0[n][0] = *(const bf16x8*)(Bc + n * 1024 + cs0);
      fb0[n][1] = *(const bf16x8*)(Bc + n * 1024 + cs1);
    }
  }

  for (int t = 0; t < NT; ++t) {
    const int cur = t & 1, nxt = cur ^ 1;
    const int kb1 = ((t + 1) << 6) & kmask;
    const int kb2 = ((t + 2) << 6) & kmask;
    const u16* Acur = As + cur * 16384 + wm * 8192;
    const u16* Bcur = Bs + cur * 16384 + (wn >> 1) * 8192 + (wn & 1) * 4096;
    const u16* Anxt = As + nxt * 16384 + wm * 8192;
    const u16* Bnxt = Bs + nxt * 16384 + (wn >> 1) * 8192 + (wn & 1) * 4096;

    // ---- p1: stage A(t+1)h1 + B(t+1)h0; read fb1; MFMA A0·B0 ----
    // (As[nxt]h1 / Bs[nxt]h0 prior contents' reads retired by p3-end of t-1)
    STAGE_A(nxt, 1, kb1);
    STAGE_B(nxt, 0, kb1);
#pragma unroll
    for (int n = 0; n < 2; ++n) {
      fb1[n][0] = *(const bf16x8*)(Bcur + (2 + n) * 1024 + cs0);
      fb1[n][1] = *(const bf16x8*)(Bcur + (2 + n) * 1024 + cs1);
    }
    __builtin_amdgcn_s_barrier();
    MFMA_Q(fa0, fb0, 0, 0);
    __builtin_amdgcn_s_barrier();

    // ---- p2: stage B(t+1)h1; read fa1; MFMA A0·B1 ----
    STAGE_B(nxt, 1, kb1);
#pragma unroll
    for (int m = 0; m < 4; ++m) {
      fa1[m][0] = *(const bf16x8*)(Acur + (4 + m) * 1024 + cs0);
      fa1[m][1] = *(const bf16x8*)(Acur + (4 + m) * 1024 + cs1);
    }
    __builtin_amdgcn_s_barrier();
    MFMA_Q(fa0, fb1, 0, 1);
    __builtin_amdgcn_s_barrier();

    // ---- p3: pure MFMA A1·B1 (LDS queue catch-up); retires fa1 reads ----
    MFMA_Q(fa1, fb1, 1, 1);
    __builtin_amdgcn_s_barrier();

    // ---- p4: stage A(t+2)h0 (safe: fa1/fa0 reads of As[cur] retired);
    //          vmcnt(2) drains A(t+1)+B(t+1); MFMA A1·B0 with tile-t fb0;
    //          THEN refill fa0/fb0 with tile t+1 fragments ----
    STAGE_A(cur, 0, kb2);
    __builtin_amdgcn_s_barrier();
    asm volatile("s_waitcnt vmcnt(2)" ::: "memory");
    MFMA_Q(fa1, fb0, 1, 0);
#pragma unroll
    for (int m = 0; m < 4; ++m) {
      fa0[m][0] = *(const bf16x8*)(Anxt + m * 1024 + cs0);
      fa0[m][1] = *(const bf16x8*)(Anxt + m * 1024 + cs1);
    }
#pragma unroll
    for (int n = 0; n < 2; ++n) {
      fb0[n][0] = *(const bf16x8*)(Bnxt + n * 1024 + cs0);
      fb0[n][1] = *(const bf16x8*)(Bnxt + n * 1024 + cs1);
    }
    __builtin_amdgcn_s_barrier();
  }

  asm volatile("s_waitcnt vmcnt(0)" ::: "memory");  // drain LDS-DMA before teardown

  // epilogue: C/D map col = lane&15, row = (lane>>4)*4 + j
  if (EP == 0 || (EP == 3 && z != 2)) {
    u16* Cb = (u16*)C;
#pragma unroll
    for (int m = 0; m < 8; ++m) {
      int gr = (int)trow + wm * 128 + m * 16 + ((lane >> 4) << 2);
#pragma unroll
      for (int n = 0; n < 4; ++n) {
        int gc = (int)tcol + wn * 64 + n * 16 + (lane & 15);
        f32x4 v = acc[m][n];
#pragma unroll
        for (int j = 0; j < 4; ++j) Cb[(size_t)(gr + j) * ldc + gc] = f2us(v[j] * scale);
      }
    }
  } else if (EP == 3) {
    // transposed store into Vt[b][d][s], 4096-row batches
    u16* Ct = (u16*)C;
#pragma unroll
    for (int m = 0; m < 8; ++m) {
      int gr = (int)trow + wm * 128 + m * 16 + ((lane >> 4) << 2);
      int b = gr >> 12;
      int sl = gr & 4095;
      u16* base = Ct + ((size_t)b << 22) + sl;
#pragma unroll
      for (int n = 0; n < 4; ++n) {
        int gc = (int)tcol + wn * 64 + n * 16 + (lane & 15);
        f32x4 v = acc[m][n];
        us4 o;
        o.x = f2us(v[0] * scale); o.y = f2us(v[1] * scale);
        o.z = f2us(v[2] * scale); o.w = f2us(v[3] * scale);
        *(us4*)(base + (size_t)gc * 4096) = o;
      }
    }
  } else {
    float* Cf = (float*)C;
#pragma unroll
    for (int m = 0; m < 8; ++m) {
      int gr = (int)trow + wm * 128 + m * 16 + ((lane >> 4) << 2);
#pragma unroll
      for (int n = 0; n < 4; ++n) {
        int gc = (int)tcol + wn * 64 + n * 16 + (lane & 15);
        f32x4 v = acc[m][n];
#pragma unroll
        for (int j = 0; j < 4; ++j) Cf[(size_t)(gr + j) * ldc + gc] = v[j] * scale;
      }
    }
  }
}

// ---------------------------------------------------------------------------
// all-batch in-place row softmax (width 4096 bf16), one block per row
// ---------------------------------------------------------------------------
__global__ __launch_bounds__(256) void softmax_all(u16* S0, u16* S1, u16* S2, u16* S3) {
  const int row = blockIdx.x;           // 0..16383
  const int b = row >> 12;
  u16* S = (b == 0) ? S0 : (b == 1) ? S1 : (b == 2) ? S2 : S3;
  const int t = threadIdx.x;
  const int lane = t & 63;
  const int wave = t >> 6;
  u16* p = S + (size_t)(row & 4095) * 4096 + t * 16;
  us8 r0 = *(const us8*)p;
  us8 r1 = *(const us8*)(p + 8);
  float f[16];
#pragma unroll
  for (int j = 0; j < 8; ++j) { f[j] = us2f(r0[j]); f[8 + j] = us2f(r1[j]); }

  float mx = f[0];
#pragma unroll
  for (int j = 1; j < 16; ++j) mx = fmaxf(mx, f[j]);
#pragma unroll
  for (int o = 32; o > 0; o >>= 1) mx = fmaxf(mx, __shfl_xor(mx, o));
  __shared__ float rmax[4], rsum[4];
  if (lane == 0) rmax[wave] = mx;
  __syncthreads();
  mx = fmaxf(fmaxf(rmax[0], rmax[1]), fmaxf(rmax[2], rmax[3]));

  float e[16], s = 0.f;
#pragma unroll
  for (int j = 0; j < 16; ++j) { e[j] = __expf(f[j] - mx); s += e[j]; }
#pragma unroll
  for (int o = 32; o > 0; o >>= 1) s += __shfl_xor(s, o);
  if (lane == 0) rsum[wave] = s;
  __syncthreads();
  s = rsum[0] + rsum[1] + rsum[2] + rsum[3];
  float inv = 1.f / s;

  us8 o0, o1;
#pragma unroll
  for (int j = 0; j < 8; ++j) { o0[j] = f2us(e[j] * inv); o1[j] = f2us(e[8 + j] * inv); }
  *(us8*)p = o0;
  *(us8*)(p + 8) = o1;
}

// ---------------------------------------------------------------------------
// orchestration
// ---------------------------------------------------------------------------
extern "C" void kernel_launch(void* const* d_in, const int* in_sizes, int n_in,
                              void* d_out, int out_size, void* d_ws, size_t ws_size,
                              hipStream_t stream) {
  (void)in_sizes; (void)n_in; (void)out_size;
  const float* x  = (const float*)d_in[0];
  const float* Wq = (const float*)d_in[1];
  const float* Wk = (const float*)d_in[2];
  const float* Wv = (const float*)d_in[3];
  const float* Wp = (const float*)d_in[4];

  if (ws_size < 209715200) return;  // need 200MB
  char* ws = (char*)d_ws;
  u16* xb  = (u16*)(ws);                      // 32MB  [0,32M)
  u16* wqb = (u16*)(ws + 33554432);           // 8MB   [32M,40M)
  u16* wkb = wqb + 1048576;
  u16* wvb = wkb + 1048576;
  u16* wpb = wvb + 1048576;
  u16* Qb  = (u16*)(ws + 41943040);           // 32MB  [40M,72M)
  u16* Kb  = (u16*)(ws + 75497472);           // 32MB  [72M,104M)
  u16* Vt  = (u16*)(ws + 109051904);          // 32MB  [104M,136M)
  u16* Ssp = (u16*)(ws + 142606336);          // 32MB  [136M,168M)
  u16* O   = (u16*)(ws + 176160768);          // 32MB  [168M,200M)

  // scores buffers: batches 0,1 in d_out (fp32 out buffer, scratch until
  // final), batch 2 in xb (dead after projections), batch 3 in Ssp
  u16* S0 = (u16*)d_out;
  u16* S1 = S0 + 16777216;
  u16* S2 = xb;
  u16* S3 = Ssp;

  // 1) bf16 conversion (x + all weights, one dispatch)
  convert_all<<<20480, 256, 0, stream>>>(x, Wq, Wk, Wv, Wp, xb, wqb);

  // 2) Q/K/V projections in one dispatch (M=16384, N=1024, K=1024; z picks W)
  gemm256<3><<<dim3(4, 64, 3), 512, 0, stream>>>(
      xb, xb, xb, xb, wqb, wkb, wvb, wvb, Qb, Kb, Vt, Vt,
      1024, 1024, 1024, 1024, 1.f);

  // 3) scores for all 4 batches (M=N=4096, K=1024)
  const u16 *Q0 = Qb, *Q1 = Qb + 4194304, *Q2 = Qb + 8388608, *Q3 = Qb + 12582912;
  const u16 *K0 = Kb, *K1 = Kb + 4194304, *K2 = Kb + 8388608, *K3 = Kb + 12582912;
  gemm256<0><<<dim3(16, 16, 4), 512, 0, stream>>>(Q0, Q1, Q2, Q3, K0, K1, K2, K3,
                                                  S0, S1, S2, S3, 1024, 1024, 1024, 4096,
                                                  1.f / 1024.f);

  // 4) softmax, all batches in one dispatch
  softmax_all<<<16384, 256, 0, stream>>>(S0, S1, S2, S3);

  // 5) PV for all batches (M=4096, N=1024, K=4096)
  const u16 *V0 = Vt, *V1 = Vt + 4194304, *V2 = Vt + 8388608, *V3 = Vt + 12582912;
  u16 *O0 = O, *O1 = O + 4194304, *O2 = O + 8388608, *O3 = O + 12582912;
  gemm256<0><<<dim3(4, 16, 4), 512, 0, stream>>>(S0, S1, S2, S3, V0, V1, V2, V3,
                                                 O0, O1, O2, O3, 4096, 4096, 4096, 1024, 1.f);

  // 6) final projection -> fp32 d_out (overwrites the S0/S1 scratch)
  gemm256<2><<<dim3(4, 64, 1), 512, 0, stream>>>(O, O, O, O, wpb, wpb, wpb, wpb,
                                                 d_out, d_out, d_out, d_out,
                                                 1024, 1024, 1024, 1024, 1.f);
}

// Round 6
// 437.957 us; speedup vs baseline: 1.2007x; 1.2007x over previous
//
#include <hip/hip_runtime.h>

typedef unsigned short u16;
typedef __attribute__((ext_vector_type(8))) short bf16x8;   // MFMA A/B frag
typedef __attribute__((ext_vector_type(4))) float f32x4;    // MFMA C/D frag
typedef __attribute__((ext_vector_type(4))) unsigned short us4;
typedef __attribute__((ext_vector_type(8))) unsigned short us8;

__device__ __forceinline__ u16 f2us(float f) {
  union { float f; unsigned u; } a; a.f = f;
  unsigned u = a.u;
  u += 0x7fffu + ((u >> 16) & 1u);   // RNE to bf16
  return (u16)(u >> 16);
}
__device__ __forceinline__ float us2f(u16 h) {
  union { unsigned u; float f; } a; a.u = ((unsigned)h) << 16;
  return a.f;
}

#define GLDS(g, l) __builtin_amdgcn_global_load_lds( \
    (const __attribute__((address_space(1))) void*)(g), \
    (__attribute__((address_space(3))) void*)(l), 16, 0, 0)

// ---------------------------------------------------------------------------
// merged fp32 -> bf16 conversion: x (16384 blocks) + 4 weights (1024 each)
// ---------------------------------------------------------------------------
__global__ __launch_bounds__(256) void convert_all(
    const float* __restrict__ x, const float* __restrict__ Wq,
    const float* __restrict__ Wk, const float* __restrict__ Wv,
    const float* __restrict__ Wp, u16* __restrict__ xb, u16* __restrict__ wb) {
  const int bid = blockIdx.x;
  const float* src;
  u16* dst;
  int off;
  if (bid < 16384) {
    src = x; dst = xb; off = bid * 256 + threadIdx.x;
  } else {
    const int w = (bid - 16384) >> 10;
    const int lb = (bid - 16384) & 1023;
    src = (w == 0) ? Wq : (w == 1) ? Wk : (w == 2) ? Wv : Wp;
    dst = wb + (size_t)w * 1048576;
    off = lb * 256 + threadIdx.x;
  }
  f32x4 v = ((const f32x4*)src)[off];
  us4 o;
  o.x = f2us(v.x); o.y = f2us(v.y); o.z = f2us(v.z); o.w = f2us(v.w);
  ((us4*)dst)[off] = o;
}

// ---------------------------------------------------------------------------
// 256x256 bf16 GEMM (C = scale * A · B^T), SINGLE barrier per phase:
// {reads; stage; s_barrier; MFMA}. Removing the post-MFMA barrier lets waves
// skew so one wave's ds_read/stage overlaps another's MFMA cluster.
// Race-freedom (single-barrier): a stage may be issued in region
// [BAR(p), BAR(p+1)) iff every read of its target region retired before some
// wave-common barrier <= BAR(p). B(t+1) stages at p1/p2 (readers at p3[t-1],
// retired pre-BAR(p4[t-1])); A(t+2) stages BOTH halves at p4 (readers at
// p2[t], retired pre-BAR(p3[t])). vmcnt ledger (stages p1:+2,p2:+2,p4:+4):
// one vmcnt(4) after p4's MFMA drains A(t+1)+B(t+1) before p1[t+1] reads,
// leaves A(t+2) in flight. Prologue (12 loads, vmcnt(4)) = steady state.
// EP: 0 = bf16 store; 2 = fp32 store; 3 = QKV mode (A fixed, B/C by z,
//     z==2 stores transposed into Vt[b][d][s], 4096-row batches).
// ---------------------------------------------------------------------------
#define MFMA_QUAD(QR, QC)                                                        \
  do {                                                                           \
    __builtin_amdgcn_s_setprio(1);                                               \
    _Pragma("unroll") for (int m = 0; m < 4; ++m)                                \
    _Pragma("unroll") for (int n = 0; n < 2; ++n)                                \
    _Pragma("unroll") for (int s = 0; s < 2; ++s)                                \
      acc[(QR)*4 + m][(QC)*2 + n] = __builtin_amdgcn_mfma_f32_16x16x32_bf16(     \
          af[(QR)*4 + m][s], bf[(QC)*2 + n][s], acc[(QR)*4 + m][(QC)*2 + n],     \
          0, 0, 0);                                                              \
    __builtin_amdgcn_s_setprio(0);                                               \
  } while (0)

#define STAGE_A(buf, h, kb)                                                  \
  do {                                                                       \
    const int su_ = (h) * 128 * lda + (kb);                                  \
    GLDS(Ap + aoff0 + su_, As + (buf) * 16384 + (h) * 8192 + ldst0);         \
    GLDS(Ap + aoff1 + su_, As + (buf) * 16384 + (h) * 8192 + ldst1);         \
  } while (0)

#define STAGE_B(buf, h, kb)                                                  \
  do {                                                                       \
    const int su_ = (h) * 128 * ldb + (kb);                                  \
    GLDS(Bp + boff0 + su_, Bs + (buf) * 16384 + (h) * 8192 + ldst0);         \
    GLDS(Bp + boff1 + su_, Bs + (buf) * 16384 + (h) * 8192 + ldst1);         \
  } while (0)

template <int EP>
__global__ __launch_bounds__(512, 2) void gemm256(
    const u16* __restrict__ A0, const u16* __restrict__ A1,
    const u16* __restrict__ A2, const u16* __restrict__ A3,
    const u16* __restrict__ B0, const u16* __restrict__ B1,
    const u16* __restrict__ B2, const u16* __restrict__ B3,
    void* C0, void* C1, void* C2, void* C3,
    int K, int lda, int ldb, int ldc, float scale) {
  __shared__ u16 As[32768];   // 2 buf x 2 half x 128x64
  __shared__ u16 Bs[32768];
  const int tid = threadIdx.x;
  const int lane = tid & 63;
  const int wid = tid >> 6;
  const int wm = wid >> 2;    // 0..1 -> A half
  const int wn = wid & 3;     // 0..3 -> 64-col slice
  const int z = blockIdx.z;
  const u16* A = (z == 0) ? A0 : (z == 1) ? A1 : (z == 2) ? A2 : A3;
  const u16* B = (z == 0) ? B0 : (z == 1) ? B1 : (z == 2) ? B2 : B3;
  void* C = (z == 0) ? C0 : (z == 1) ? C1 : (z == 2) ? C2 : C3;

  // T1: bijective XCD swizzle (all grids have nwg % 8 == 0)
  const int gx = gridDim.x;
  const int nwg = gx * (int)gridDim.y;
  const int orig = (int)blockIdx.y * gx + (int)blockIdx.x;
  const int swz = (orig & 7) * (nwg >> 3) + (orig >> 3);
  const long trow = (long)(swz / gx) * 256;
  const long tcol = (long)(swz % gx) * 256;

  // hoisted per-thread staging offsets (u16 elements)
  const int srow = tid >> 3;                     // 0..63
  const int sgrp = (tid & 7) ^ (srow & 7);       // inverse T2 swizzle on source
  const int aoff0 = srow * lda + sgrp * 8;
  const int aoff1 = aoff0 + (lda << 6);
  const int boff0 = srow * ldb + sgrp * 8;
  const int boff1 = boff0 + (ldb << 6);
  const int ldst0 = (tid & ~63) * 8;             // wave-uniform LDS dest
  const int ldst1 = ldst0 + 4096;
  const u16* Ap = A + trow * lda;
  const u16* Bp = B + tcol * ldb;

  // hoisted per-lane LDS read offsets (u16 elements): row + swizzled col
  const int l15x64 = (lane & 15) * 64;
  const int cs0 = ((((lane >> 4) * 8)) ^ ((lane & 7) * 8)) + l15x64;
  const int cs1 = ((32 + ((lane >> 4) * 8)) ^ ((lane & 7) * 8)) + l15x64;

  f32x4 acc[8][4];
  f32x4 zero = {0.f, 0.f, 0.f, 0.f};
#pragma unroll
  for (int m = 0; m < 8; ++m)
#pragma unroll
    for (int n = 0; n < 4; ++n) acc[m][n] = zero;

  const int NT = K >> 6;
  const int kmask = K - 1;   // K is a power of two

  // prologue: stage A(0), B(0), A(1) (12 loads); vmcnt(4) leaves A(1);
  STAGE_A(0, 0, 0);
  STAGE_A(0, 1, 0);
  STAGE_B(0, 0, 0);
  STAGE_B(0, 1, 0);
  STAGE_A(1, 0, 64 & kmask);
  STAGE_A(1, 1, 64 & kmask);
  asm volatile("s_waitcnt vmcnt(4)" ::: "memory");
  __builtin_amdgcn_s_barrier();

  for (int t = 0; t < NT; ++t) {
    const int cur = t & 1, nxt = cur ^ 1;
    const int kb1 = ((t + 1) << 6) & kmask;
    const int kb2 = ((t + 2) << 6) & kmask;
    const u16* Acur = As + cur * 16384 + wm * 8192;
    const u16* Bcur = Bs + cur * 16384 + (wn >> 1) * 8192 + (wn & 1) * 4096;
    bf16x8 af[8][2], bf[4][2];

    // ---- p1: read A-qr0 + B-qc0; stage B(t+1)h0; BAR; MFMA (0,0) ----
#pragma unroll
    for (int m = 0; m < 4; ++m) {
      af[m][0] = *(const bf16x8*)(Acur + m * 1024 + cs0);
      af[m][1] = *(const bf16x8*)(Acur + m * 1024 + cs1);
    }
#pragma unroll
    for (int n = 0; n < 2; ++n) {
      bf[n][0] = *(const bf16x8*)(Bcur + n * 1024 + cs0);
      bf[n][1] = *(const bf16x8*)(Bcur + n * 1024 + cs1);
    }
    STAGE_B(nxt, 0, kb1);
    __builtin_amdgcn_s_barrier();
    MFMA_QUAD(0, 0);

    // ---- p2: read A-qr1; stage B(t+1)h1; BAR; MFMA (1,0) ----
#pragma unroll
    for (int m = 0; m < 4; ++m) {
      af[4 + m][0] = *(const bf16x8*)(Acur + (4 + m) * 1024 + cs0);
      af[4 + m][1] = *(const bf16x8*)(Acur + (4 + m) * 1024 + cs1);
    }
    STAGE_B(nxt, 1, kb1);
    __builtin_amdgcn_s_barrier();
    MFMA_QUAD(1, 0);

    // ---- p3: read B-qc1; BAR; MFMA (0,1) ----
#pragma unroll
    for (int n = 0; n < 2; ++n) {
      bf[2 + n][0] = *(const bf16x8*)(Bcur + (2 + n) * 1024 + cs0);
      bf[2 + n][1] = *(const bf16x8*)(Bcur + (2 + n) * 1024 + cs1);
    }
    __builtin_amdgcn_s_barrier();
    MFMA_QUAD(0, 1);

    // ---- p4: stage A(t+2) both halves (readers of As[cur] retired
    //          pre-BAR(p3)); BAR; MFMA (1,1); vmcnt(4) before p1[t+1] ----
    STAGE_A(cur, 0, kb2);
    STAGE_A(cur, 1, kb2);
    __builtin_amdgcn_s_barrier();
    MFMA_QUAD(1, 1);
    asm volatile("s_waitcnt vmcnt(4)" ::: "memory");
  }

  asm volatile("s_waitcnt vmcnt(0)" ::: "memory");  // drain LDS-DMA before teardown

  // epilogue: C/D map col = lane&15, row = (lane>>4)*4 + j
  if (EP == 0 || (EP == 3 && z != 2)) {
    u16* Cb = (u16*)C;
#pragma unroll
    for (int m = 0; m < 8; ++m) {
      int gr = (int)trow + wm * 128 + m * 16 + ((lane >> 4) << 2);
#pragma unroll
      for (int n = 0; n < 4; ++n) {
        int gc = (int)tcol + wn * 64 + n * 16 + (lane & 15);
        f32x4 v = acc[m][n];
#pragma unroll
        for (int j = 0; j < 4; ++j) Cb[(size_t)(gr + j) * ldc + gc] = f2us(v[j] * scale);
      }
    }
  } else if (EP == 3) {
    // transposed store into Vt[b][d][s], 4096-row batches
    u16* Ct = (u16*)C;
#pragma unroll
    for (int m = 0; m < 8; ++m) {
      int gr = (int)trow + wm * 128 + m * 16 + ((lane >> 4) << 2);
      int b = gr >> 12;
      int sl = gr & 4095;
      u16* base = Ct + ((size_t)b << 22) + sl;
#pragma unroll
      for (int n = 0; n < 4; ++n) {
        int gc = (int)tcol + wn * 64 + n * 16 + (lane & 15);
        f32x4 v = acc[m][n];
        us4 o;
        o.x = f2us(v[0] * scale); o.y = f2us(v[1] * scale);
        o.z = f2us(v[2] * scale); o.w = f2us(v[3] * scale);
        *(us4*)(base + (size_t)gc * 4096) = o;
      }
    }
  } else {
    float* Cf = (float*)C;
#pragma unroll
    for (int m = 0; m < 8; ++m) {
      int gr = (int)trow + wm * 128 + m * 16 + ((lane >> 4) << 2);
#pragma unroll
      for (int n = 0; n < 4; ++n) {
        int gc = (int)tcol + wn * 64 + n * 16 + (lane & 15);
        f32x4 v = acc[m][n];
#pragma unroll
        for (int j = 0; j < 4; ++j) Cf[(size_t)(gr + j) * ldc + gc] = v[j] * scale;
      }
    }
  }
}

// ---------------------------------------------------------------------------
// all-batch in-place row softmax (width 4096 bf16), one block per row
// ---------------------------------------------------------------------------
__global__ __launch_bounds__(256) void softmax_all(u16* S0, u16* S1, u16* S2, u16* S3) {
  const int row = blockIdx.x;           // 0..16383
  const int b = row >> 12;
  u16* S = (b == 0) ? S0 : (b == 1) ? S1 : (b == 2) ? S2 : S3;
  const int t = threadIdx.x;
  const int lane = t & 63;
  const int wave = t >> 6;
  u16* p = S + (size_t)(row & 4095) * 4096 + t * 16;
  us8 r0 = *(const us8*)p;
  us8 r1 = *(const us8*)(p + 8);
  float f[16];
#pragma unroll
  for (int j = 0; j < 8; ++j) { f[j] = us2f(r0[j]); f[8 + j] = us2f(r1[j]); }

  float mx = f[0];
#pragma unroll
  for (int j = 1; j < 16; ++j) mx = fmaxf(mx, f[j]);
#pragma unroll
  for (int o = 32; o > 0; o >>= 1) mx = fmaxf(mx, __shfl_xor(mx, o));
  __shared__ float rmax[4], rsum[4];
  if (lane == 0) rmax[wave] = mx;
  __syncthreads();
  mx = fmaxf(fmaxf(rmax[0], rmax[1]), fmaxf(rmax[2], rmax[3]));

  float e[16], s = 0.f;
#pragma unroll
  for (int j = 0; j < 16; ++j) { e[j] = __expf(f[j] - mx); s += e[j]; }
#pragma unroll
  for (int o = 32; o > 0; o >>= 1) s += __shfl_xor(s, o);
  if (lane == 0) rsum[wave] = s;
  __syncthreads();
  s = rsum[0] + rsum[1] + rsum[2] + rsum[3];
  float inv = 1.f / s;

  us8 o0, o1;
#pragma unroll
  for (int j = 0; j < 8; ++j) { o0[j] = f2us(e[j] * inv); o1[j] = f2us(e[8 + j] * inv); }
  *(us8*)p = o0;
  *(us8*)(p + 8) = o1;
}

// ---------------------------------------------------------------------------
// orchestration
// ---------------------------------------------------------------------------
extern "C" void kernel_launch(void* const* d_in, const int* in_sizes, int n_in,
                              void* d_out, int out_size, void* d_ws, size_t ws_size,
                              hipStream_t stream) {
  (void)in_sizes; (void)n_in; (void)out_size;
  const float* x  = (const float*)d_in[0];
  const float* Wq = (const float*)d_in[1];
  const float* Wk = (const float*)d_in[2];
  const float* Wv = (const float*)d_in[3];
  const float* Wp = (const float*)d_in[4];

  if (ws_size < 209715200) return;  // need 200MB
  char* ws = (char*)d_ws;
  u16* xb  = (u16*)(ws);                      // 32MB  [0,32M)
  u16* wqb = (u16*)(ws + 33554432);           // 8MB   [32M,40M)
  u16* wkb = wqb + 1048576;
  u16* wvb = wkb + 1048576;
  u16* wpb = wvb + 1048576;
  u16* Qb  = (u16*)(ws + 41943040);           // 32MB  [40M,72M)
  u16* Kb  = (u16*)(ws + 75497472);           // 32MB  [72M,104M)
  u16* Vt  = (u16*)(ws + 109051904);          // 32MB  [104M,136M)
  u16* Ssp = (u16*)(ws + 142606336);          // 32MB  [136M,168M)
  u16* O   = (u16*)(ws + 176160768);          // 32MB  [168M,200M)

  // scores buffers: batches 0,1 in d_out (fp32 out buffer, scratch until
  // final), batch 2 in xb (dead after projections), batch 3 in Ssp
  u16* S0 = (u16*)d_out;
  u16* S1 = S0 + 16777216;
  u16* S2 = xb;
  u16* S3 = Ssp;

  // 1) bf16 conversion (x + all weights, one dispatch)
  convert_all<<<20480, 256, 0, stream>>>(x, Wq, Wk, Wv, Wp, xb, wqb);

  // 2) Q/K/V projections in one dispatch (M=16384, N=1024, K=1024; z picks W)
  gemm256<3><<<dim3(4, 64, 3), 512, 0, stream>>>(
      xb, xb, xb, xb, wqb, wkb, wvb, wvb, Qb, Kb, Vt, Vt,
      1024, 1024, 1024, 1024, 1.f);

  // 3) scores for all 4 batches (M=N=4096, K=1024)
  const u16 *Q0 = Qb, *Q1 = Qb + 4194304, *Q2 = Qb + 8388608, *Q3 = Qb + 12582912;
  const u16 *K0 = Kb, *K1 = Kb + 4194304, *K2 = Kb + 8388608, *K3 = Kb + 12582912;
  gemm256<0><<<dim3(16, 16, 4), 512, 0, stream>>>(Q0, Q1, Q2, Q3, K0, K1, K2, K3,
                                                  S0, S1, S2, S3, 1024, 1024, 1024, 4096,
                                                  1.f / 1024.f);

  // 4) softmax, all batches in one dispatch
  softmax_all<<<16384, 256, 0, stream>>>(S0, S1, S2, S3);

  // 5) PV for all batches (M=4096, N=1024, K=4096)
  const u16 *V0 = Vt, *V1 = Vt + 4194304, *V2 = Vt + 8388608, *V3 = Vt + 12582912;
  u16 *O0 = O, *O1 = O + 4194304, *O2 = O + 8388608, *O3 = O + 12582912;
  gemm256<0><<<dim3(4, 16, 4), 512, 0, stream>>>(S0, S1, S2, S3, V0, V1, V2, V3,
                                                 O0, O1, O2, O3, 4096, 4096, 4096, 1024, 1.f);

  // 6) final projection -> fp32 d_out (overwrites the S0/S1 scratch)
  gemm256<2><<<dim3(4, 64, 1), 512, 0, stream>>>(O, O, O, O, wpb, wpb, wpb, wpb,
                                                 d_out, d_out, d_out, d_out,
                                                 1024, 1024, 1024, 1024, 1.f);
}